// Round 1
// baseline (15669.081 us; speedup 1.0000x reference)
//
#include <hip/hip_runtime.h>
#include <math.h>

#define NSTEP 4095   // T-1 sequence steps
#define EDIM  512
#define HDIM  1024
#define GDIM  4096   // 4*H
#define KDIM  1024   // 2E == H == 1024 for both GEMMs
#define CDIM  1221
#define SNWG  256    // scan workgroups (4 hidden units each, 1 unit per wave)
#define SNT   256    // scan threads per WG (4 waves)

__device__ __forceinline__ float sigmoidf_(float v) {
    return 1.0f / (1.0f + __expf(-v));
}
__device__ __forceinline__ float tanhf_(float v) {
    v = fminf(fmaxf(v, -15.0f), 15.0f);      // avoid inf/inf NaN
    const float e2 = __expf(2.0f * v);
    return (e2 - 1.0f) / (e2 + 1.0f);
}

// ---------------------------------------------------------------------------
// GEMM1: xg[m][n] = sum_k A[m][k]*W_ih[n][k] + b_ih[n] + b_hh[n]
//   A[m][k] = emb[x[m]][k] (k<512) ; emb[x[4095]][k-512] (k>=512)
// ---------------------------------------------------------------------------
__global__ __launch_bounds__(256) void gemm_emb_kernel(
    const int* __restrict__ x, const float* __restrict__ emb,
    const float* __restrict__ W, const float* __restrict__ b_ih,
    const float* __restrict__ b_hh, float* __restrict__ xg)
{
    __shared__ float As[8][128];
    __shared__ float Bs[8][128];
    const int tid = threadIdx.x;
    const int bm = blockIdx.y * 128, bn = blockIdx.x * 128;
    const int tx = tid & 15, ty = tid >> 4;
    const int lrow = tid >> 1;
    const int lk4  = (tid & 1) * 4;
    const int lastTok = x[NSTEP];
    const int am = bm + lrow;
    const int tokRow = (am < NSTEP) ? x[am] : 0;
    const int bnrow = bn + lrow;

    float acc[8][8];
#pragma unroll
    for (int i = 0; i < 8; ++i)
#pragma unroll
        for (int j = 0; j < 8; ++j) acc[i][j] = 0.0f;

    for (int k0 = 0; k0 < KDIM; k0 += 8) {
        const int k = k0 + lk4;
        float4 av = make_float4(0.f, 0.f, 0.f, 0.f);
        if (am < NSTEP) {
            const int tok = (k < EDIM) ? tokRow : lastTok;
            const int kk  = (k < EDIM) ? k : (k - EDIM);
            av = *(const float4*)(emb + (size_t)tok * EDIM + kk);
        }
        const float4 bv = *(const float4*)(W + (size_t)bnrow * KDIM + k);
        __syncthreads();
        As[lk4 + 0][lrow] = av.x; As[lk4 + 1][lrow] = av.y;
        As[lk4 + 2][lrow] = av.z; As[lk4 + 3][lrow] = av.w;
        Bs[lk4 + 0][lrow] = bv.x; Bs[lk4 + 1][lrow] = bv.y;
        Bs[lk4 + 2][lrow] = bv.z; Bs[lk4 + 3][lrow] = bv.w;
        __syncthreads();
#pragma unroll
        for (int kk = 0; kk < 8; ++kk) {
            const float4 a0 = *(const float4*)&As[kk][ty * 4];
            const float4 a1 = *(const float4*)&As[kk][ty * 4 + 64];
            const float4 b0 = *(const float4*)&Bs[kk][tx * 4];
            const float4 b1 = *(const float4*)&Bs[kk][tx * 4 + 64];
            const float a[8] = {a0.x, a0.y, a0.z, a0.w, a1.x, a1.y, a1.z, a1.w};
            const float b[8] = {b0.x, b0.y, b0.z, b0.w, b1.x, b1.y, b1.z, b1.w};
#pragma unroll
            for (int i = 0; i < 8; ++i)
#pragma unroll
                for (int j = 0; j < 8; ++j) acc[i][j] += a[i] * b[j];
        }
    }
#pragma unroll
    for (int i = 0; i < 8; ++i) {
        const int m = bm + ((i < 4) ? (ty * 4 + i) : (64 + ty * 4 + i - 4));
        if (m >= NSTEP) continue;
#pragma unroll
        for (int j = 0; j < 8; ++j) {
            const int n = bn + ((j < 4) ? (tx * 4 + j) : (64 + tx * 4 + j - 4));
            xg[(size_t)m * GDIM + n] = acc[i][j] + b_ih[n] + b_hh[n];
        }
    }
}

// ---------------------------------------------------------------------------
// GEMM2: out[m][n] = sum_k hs[m][k]*W_out[n][k] + b_out[n]   (N=1221)
// ---------------------------------------------------------------------------
__global__ __launch_bounds__(256) void gemm_out_kernel(
    const float* __restrict__ A, const float* __restrict__ W,
    const float* __restrict__ bias, float* __restrict__ C)
{
    __shared__ float As[8][128];
    __shared__ float Bs[8][128];
    const int tid = threadIdx.x;
    const int bm = blockIdx.y * 128, bn = blockIdx.x * 128;
    const int tx = tid & 15, ty = tid >> 4;
    const int lrow = tid >> 1;
    const int lk4  = (tid & 1) * 4;
    const int am = bm + lrow;
    const int bnrow = bn + lrow;

    float acc[8][8];
#pragma unroll
    for (int i = 0; i < 8; ++i)
#pragma unroll
        for (int j = 0; j < 8; ++j) acc[i][j] = 0.0f;

    for (int k0 = 0; k0 < KDIM; k0 += 8) {
        const int k = k0 + lk4;
        float4 av = make_float4(0.f, 0.f, 0.f, 0.f);
        if (am < NSTEP) av = *(const float4*)(A + (size_t)am * KDIM + k);
        float4 bv = make_float4(0.f, 0.f, 0.f, 0.f);
        if (bnrow < CDIM) bv = *(const float4*)(W + (size_t)bnrow * KDIM + k);
        __syncthreads();
        As[lk4 + 0][lrow] = av.x; As[lk4 + 1][lrow] = av.y;
        As[lk4 + 2][lrow] = av.z; As[lk4 + 3][lrow] = av.w;
        Bs[lk4 + 0][lrow] = bv.x; Bs[lk4 + 1][lrow] = bv.y;
        Bs[lk4 + 2][lrow] = bv.z; Bs[lk4 + 3][lrow] = bv.w;
        __syncthreads();
#pragma unroll
        for (int kk = 0; kk < 8; ++kk) {
            const float4 a0 = *(const float4*)&As[kk][ty * 4];
            const float4 a1 = *(const float4*)&As[kk][ty * 4 + 64];
            const float4 b0 = *(const float4*)&Bs[kk][tx * 4];
            const float4 b1 = *(const float4*)&Bs[kk][tx * 4 + 64];
            const float a[8] = {a0.x, a0.y, a0.z, a0.w, a1.x, a1.y, a1.z, a1.w};
            const float b[8] = {b0.x, b0.y, b0.z, b0.w, b1.x, b1.y, b1.z, b1.w};
#pragma unroll
            for (int i = 0; i < 8; ++i)
#pragma unroll
                for (int j = 0; j < 8; ++j) acc[i][j] += a[i] * b[j];
        }
    }
#pragma unroll
    for (int i = 0; i < 8; ++i) {
        const int m = bm + ((i < 4) ? (ty * 4 + i) : (64 + ty * 4 + i - 4));
        if (m >= NSTEP) continue;
#pragma unroll
        for (int j = 0; j < 8; ++j) {
            const int n = bn + ((j < 4) ? (tx * 4 + j) : (64 + tx * 4 + j - 4));
            if (n < CDIM) C[(size_t)m * CDIM + n] = acc[i][j] + bias[n];
        }
    }
}

// ---------------------------------------------------------------------------
// Persistent LSTM scan, v4. 256 WGs x 256 threads (4 waves); wave w owns
// hidden unit blockIdx.x*4+w (all 4 gate rows of that unit -> the whole
// gate->nonlin->publish tail is wave-local: no gate_s, no 2nd barrier,
// no 16-thread serial section).
//   - Per-CU LDS-GEMV traffic cut 4x vs v3 (16 rows x 4KB per WG) and the
//     GEMV now runs on 256 CUs instead of 64.
//   - Handoff: same tagged 64-bit payloads hb[parity][i] = (step<<32)|bits(h).
//     Each thread polls 4 words with a pending-mask (batched loads: one
//     memory latency per round). Parity double-buffer h_s[2][1024]; the
//     single per-step barrier + handoff ordering make t+2's h_s writes safe
//     against t's reads (WG passes barrier(t+1) only after all its waves
//     finished reading h_s[par] at t).
//   - c state kept redundantly in every lane of the wave (bit-identical).
// ---------------------------------------------------------------------------
__global__ __launch_bounds__(256) void scan_kernel(
    const float* __restrict__ xg, const float* __restrict__ Whh,
    float* __restrict__ hs, unsigned long long* hb)
{
    __shared__ float h_s[2][HDIM];
    const int tid  = threadIdx.x;
    const int wv   = tid >> 6;           // wave 0..3
    const int lane = tid & 63;
    const int q    = lane >> 4;          // gate row 0..3 (i,f,g,o)
    const int seg  = lane & 15;          // 16 segs x 64 cols
    const int unit = blockIdx.x * 4 + wv;
    const int grow = q * HDIM + unit;    // row in W_hh

    // weights: lane covers cols j*64 + seg*4 .. +3, j = 0..15 (64 VGPRs)
    float4 w4[16];
#pragma unroll
    for (int j = 0; j < 16; ++j)
        w4[j] = *(const float4*)(Whh + (size_t)grow * KDIM + j * 64 + seg * 4);
#pragma unroll
    for (int j = 0; j < 16; ++j)
        asm volatile("" : "+v"(w4[j].x), "+v"(w4[j].y), "+v"(w4[j].z), "+v"(w4[j].w));

    for (int i = tid; i < HDIM; i += SNT) h_s[0][i] = 0.0f;
    __syncthreads();

    float c = 0.0f;                      // redundant per-lane cell state

    for (int t = 1; t <= NSTEP; ++t) {
        const int par = (t - 1) & 1;

        // xg load overlaps the spin below (independent)
        float xgv = 0.0f;
        if (seg == 0) xgv = xg[(size_t)(t - 1) * GDIM + grow];

        if (t > 1) {
            const int want = t - 1;
            const unsigned long long* p = hb + (size_t)par * HDIM + tid;
            unsigned long long v0 = 0, v1 = 0, v2 = 0, v3 = 0;
            unsigned pend = 0xFu;
            do {
                if (pend & 1u) v0 = __hip_atomic_load(p,       __ATOMIC_RELAXED, __HIP_MEMORY_SCOPE_AGENT);
                if (pend & 2u) v1 = __hip_atomic_load(p + 256, __ATOMIC_RELAXED, __HIP_MEMORY_SCOPE_AGENT);
                if (pend & 4u) v2 = __hip_atomic_load(p + 512, __ATOMIC_RELAXED, __HIP_MEMORY_SCOPE_AGENT);
                if (pend & 8u) v3 = __hip_atomic_load(p + 768, __ATOMIC_RELAXED, __HIP_MEMORY_SCOPE_AGENT);
                if ((pend & 1u) && (int)(v0 >> 32) == want) pend &= ~1u;
                if ((pend & 2u) && (int)(v1 >> 32) == want) pend &= ~2u;
                if ((pend & 4u) && (int)(v2 >> 32) == want) pend &= ~4u;
                if ((pend & 8u) && (int)(v3 >> 32) == want) pend &= ~8u;
            } while (pend);
            h_s[par][tid      ] = __uint_as_float((unsigned)v0);
            h_s[par][tid + 256] = __uint_as_float((unsigned)v1);
            h_s[par][tid + 512] = __uint_as_float((unsigned)v2);
            h_s[par][tid + 768] = __uint_as_float((unsigned)v3);
        }
        __syncthreads();   // (B) h_s[par] ready; also fences t-1's reads (see header)

        // GEMV: this lane's 64 columns of its gate row
        float acc = xgv;
#pragma unroll
        for (int j = 0; j < 16; ++j) {
            const float4 h4 = *(const float4*)&h_s[par][j * 64 + seg * 4];
            acc += w4[j].x * h4.x + w4[j].y * h4.y +
                   w4[j].z * h4.z + w4[j].w * h4.w;
        }
        // 4-stage butterfly over the 16 segs: every lane gets its row's sum
        acc += __shfl_xor(acc, 1, 64);
        acc += __shfl_xor(acc, 2, 64);
        acc += __shfl_xor(acc, 4, 64);
        acc += __shfl_xor(acc, 8, 64);
        // gather the 4 gate sums (constant lanes -> v_readlane broadcasts)
        const float g0 = __shfl(acc,  0, 64);   // i
        const float g1 = __shfl(acc, 16, 64);   // f
        const float g2 = __shfl(acc, 32, 64);   // g
        const float g3 = __shfl(acc, 48, 64);   // o

        const float ig = sigmoidf_(g0);
        const float fg = sigmoidf_(g1);
        const float gg = tanhf_(g2);
        const float og = sigmoidf_(g3);
        c = fg * c + ig * gg;
        const float h = og * tanhf_(c);

        if (lane == 0) {
            hs[(size_t)(t - 1) * HDIM + unit] = h;
            const unsigned long long pv =
                ((unsigned long long)(unsigned)t << 32) | __float_as_uint(h);
            __hip_atomic_store(&hb[(size_t)(t & 1) * HDIM + unit], pv,
                               __ATOMIC_RELAXED, __HIP_MEMORY_SCOPE_AGENT);
        }
        // no trailing barrier: next-iter h_s[par^1] writes are WAR-safe via
        // parity; h_s[par] rewrite at t+2 is gated by barrier(t+1).
    }
}

extern "C" void kernel_launch(void* const* d_in, const int* in_sizes, int n_in,
                              void* d_out, int out_size, void* d_ws, size_t ws_size,
                              hipStream_t stream)
{
    const int*   x     = (const int*)d_in[0];
    const float* emb   = (const float*)d_in[1];
    const float* W_ih  = (const float*)d_in[2];
    const float* W_hh  = (const float*)d_in[3];
    const float* b_ih  = (const float*)d_in[4];
    const float* b_hh  = (const float*)d_in[5];
    const float* W_out = (const float*)d_in[6];
    const float* b_out = (const float*)d_in[7];
    float* out = (float*)d_out;

    float* xg = (float*)d_ws;                          // 4095*4096 f32
    float* hs = xg + (size_t)NSTEP * GDIM;             // 4095*1024 f32
    unsigned long long* hb =
        (unsigned long long*)(hs + (size_t)NSTEP * HDIM);  // 2*1024 u64 (8B aligned)

    dim3 blk(256);
    dim3 g1(GDIM / 128, 32);                           // 32 x 32
    gemm_emb_kernel<<<g1, blk, 0, stream>>>(x, emb, W_ih, b_ih, b_hh, xg);

    scan_kernel<<<dim3(SNWG), dim3(SNT), 0, stream>>>(xg, W_hh, hs, hb);

    dim3 g2((CDIM + 127) / 128, 32);                   // 10 x 32
    gemm_out_kernel<<<g2, blk, 0, stream>>>(hs, W_out, b_out, out);
}

// Round 2
// 14700.287 us; speedup vs baseline: 1.0659x; 1.0659x over previous
//
#include <hip/hip_runtime.h>
#include <math.h>

#define NSTEP 4095   // T-1 sequence steps
#define EDIM  512
#define HDIM  1024
#define GDIM  4096   // 4*H
#define KDIM  1024   // 2E == H == 1024 for both GEMMs
#define CDIM  1221
#define SNWG  64     // scan workgroups (16 units each) -- proven poll fanout
#define SNT   512    // scan threads per WG (8 waves)
#define HPAD  36     // 32 cols + 4 pad per segment (bank-conflict-free)

__device__ __forceinline__ float sigmoidf_(float v) {
    return 1.0f / (1.0f + __expf(-v));
}
__device__ __forceinline__ float tanhf_(float v) {
    v = fminf(fmaxf(v, -15.0f), 15.0f);      // avoid inf/inf NaN
    const float e2 = __expf(2.0f * v);
    return (e2 - 1.0f) / (e2 + 1.0f);
}

// ---------------------------------------------------------------------------
// GEMM1: xg[m][n] = sum_k A[m][k]*W_ih[n][k] + b_ih[n] + b_hh[n]
//   A[m][k] = emb[x[m]][k] (k<512) ; emb[x[4095]][k-512] (k>=512)
// ---------------------------------------------------------------------------
__global__ __launch_bounds__(256) void gemm_emb_kernel(
    const int* __restrict__ x, const float* __restrict__ emb,
    const float* __restrict__ W, const float* __restrict__ b_ih,
    const float* __restrict__ b_hh, float* __restrict__ xg)
{
    __shared__ float As[8][128];
    __shared__ float Bs[8][128];
    const int tid = threadIdx.x;
    const int bm = blockIdx.y * 128, bn = blockIdx.x * 128;
    const int tx = tid & 15, ty = tid >> 4;
    const int lrow = tid >> 1;
    const int lk4  = (tid & 1) * 4;
    const int lastTok = x[NSTEP];
    const int am = bm + lrow;
    const int tokRow = (am < NSTEP) ? x[am] : 0;
    const int bnrow = bn + lrow;

    float acc[8][8];
#pragma unroll
    for (int i = 0; i < 8; ++i)
#pragma unroll
        for (int j = 0; j < 8; ++j) acc[i][j] = 0.0f;

    for (int k0 = 0; k0 < KDIM; k0 += 8) {
        const int k = k0 + lk4;
        float4 av = make_float4(0.f, 0.f, 0.f, 0.f);
        if (am < NSTEP) {
            const int tok = (k < EDIM) ? tokRow : lastTok;
            const int kk  = (k < EDIM) ? k : (k - EDIM);
            av = *(const float4*)(emb + (size_t)tok * EDIM + kk);
        }
        const float4 bv = *(const float4*)(W + (size_t)bnrow * KDIM + k);
        __syncthreads();
        As[lk4 + 0][lrow] = av.x; As[lk4 + 1][lrow] = av.y;
        As[lk4 + 2][lrow] = av.z; As[lk4 + 3][lrow] = av.w;
        Bs[lk4 + 0][lrow] = bv.x; Bs[lk4 + 1][lrow] = bv.y;
        Bs[lk4 + 2][lrow] = bv.z; Bs[lk4 + 3][lrow] = bv.w;
        __syncthreads();
#pragma unroll
        for (int kk = 0; kk < 8; ++kk) {
            const float4 a0 = *(const float4*)&As[kk][ty * 4];
            const float4 a1 = *(const float4*)&As[kk][ty * 4 + 64];
            const float4 b0 = *(const float4*)&Bs[kk][tx * 4];
            const float4 b1 = *(const float4*)&Bs[kk][tx * 4 + 64];
            const float a[8] = {a0.x, a0.y, a0.z, a0.w, a1.x, a1.y, a1.z, a1.w};
            const float b[8] = {b0.x, b0.y, b0.z, b0.w, b1.x, b1.y, b1.z, b1.w};
#pragma unroll
            for (int i = 0; i < 8; ++i)
#pragma unroll
                for (int j = 0; j < 8; ++j) acc[i][j] += a[i] * b[j];
        }
    }
#pragma unroll
    for (int i = 0; i < 8; ++i) {
        const int m = bm + ((i < 4) ? (ty * 4 + i) : (64 + ty * 4 + i - 4));
        if (m >= NSTEP) continue;
#pragma unroll
        for (int j = 0; j < 8; ++j) {
            const int n = bn + ((j < 4) ? (tx * 4 + j) : (64 + tx * 4 + j - 4));
            xg[(size_t)m * GDIM + n] = acc[i][j] + b_ih[n] + b_hh[n];
        }
    }
}

// ---------------------------------------------------------------------------
// GEMM2: out[m][n] = sum_k hs[m][k]*W_out[n][k] + b_out[n]   (N=1221)
// ---------------------------------------------------------------------------
__global__ __launch_bounds__(256) void gemm_out_kernel(
    const float* __restrict__ A, const float* __restrict__ W,
    const float* __restrict__ bias, float* __restrict__ C)
{
    __shared__ float As[8][128];
    __shared__ float Bs[8][128];
    const int tid = threadIdx.x;
    const int bm = blockIdx.y * 128, bn = blockIdx.x * 128;
    const int tx = tid & 15, ty = tid >> 4;
    const int lrow = tid >> 1;
    const int lk4  = (tid & 1) * 4;
    const int am = bm + lrow;
    const int bnrow = bn + lrow;

    float acc[8][8];
#pragma unroll
    for (int i = 0; i < 8; ++i)
#pragma unroll
        for (int j = 0; j < 8; ++j) acc[i][j] = 0.0f;

    for (int k0 = 0; k0 < KDIM; k0 += 8) {
        const int k = k0 + lk4;
        float4 av = make_float4(0.f, 0.f, 0.f, 0.f);
        if (am < NSTEP) av = *(const float4*)(A + (size_t)am * KDIM + k);
        float4 bv = make_float4(0.f, 0.f, 0.f, 0.f);
        if (bnrow < CDIM) bv = *(const float4*)(W + (size_t)bnrow * KDIM + k);
        __syncthreads();
        As[lk4 + 0][lrow] = av.x; As[lk4 + 1][lrow] = av.y;
        As[lk4 + 2][lrow] = av.z; As[lk4 + 3][lrow] = av.w;
        Bs[lk4 + 0][lrow] = bv.x; Bs[lk4 + 1][lrow] = bv.y;
        Bs[lk4 + 2][lrow] = bv.z; Bs[lk4 + 3][lrow] = bv.w;
        __syncthreads();
#pragma unroll
        for (int kk = 0; kk < 8; ++kk) {
            const float4 a0 = *(const float4*)&As[kk][ty * 4];
            const float4 a1 = *(const float4*)&As[kk][ty * 4 + 64];
            const float4 b0 = *(const float4*)&Bs[kk][tx * 4];
            const float4 b1 = *(const float4*)&Bs[kk][tx * 4 + 64];
            const float a[8] = {a0.x, a0.y, a0.z, a0.w, a1.x, a1.y, a1.z, a1.w};
            const float b[8] = {b0.x, b0.y, b0.z, b0.w, b1.x, b1.y, b1.z, b1.w};
#pragma unroll
            for (int i = 0; i < 8; ++i)
#pragma unroll
                for (int j = 0; j < 8; ++j) acc[i][j] += a[i] * b[j];
        }
    }
#pragma unroll
    for (int i = 0; i < 8; ++i) {
        const int m = bm + ((i < 4) ? (ty * 4 + i) : (64 + ty * 4 + i - 4));
        if (m >= NSTEP) continue;
#pragma unroll
        for (int j = 0; j < 8; ++j) {
            const int n = bn + ((j < 4) ? (tx * 4 + j) : (64 + tx * 4 + j - 4));
            if (n < CDIM) C[(size_t)m * CDIM + n] = acc[i][j] + bias[n];
        }
    }
}

// ---------------------------------------------------------------------------
// Persistent LSTM scan, v5. 64 WGs x 512 threads (8 waves); WG g owns units
// g*16..g*16+15. Thread (u = tid>>5, s = tid&31) holds ALL FOUR gate rows of
// unit u restricted to columns s*32..s*32+31 (4x8 float4 = 128 weight VGPRs).
//   - Each h4 LDS read is reused for 4 gate rows: per-CU LDS read drops
//     256KB -> 64KB per step vs v3 (the v3 step's dominant cost), while the
//     poll fanout stays at v3's proven 64 WGs x 1024 words (v4's 256-WG
//     fanout tripled FETCH_SIZE and doubled step time -- reverted).
//   - h_s stored seg-major with +4 pad (HPAD=36): reads 4 lanes/slot-group
//     (b128 intrinsic minimum), writes conflict-free.
//   - Tail is wave-local: 5-stage butterfly over the 32-lane unit-group,
//     nonlinearity redundant in all lanes, lane s==0 publishes. One barrier
//     per step; no gate_s, no serial 16-thread section.
//   - Handoff unchanged: tagged payloads hb[par][i] = (step<<32)|bits(h),
//     parity double-buffer, 2-step production slack. Poison tag never
//     matches a wanted step.
// ---------------------------------------------------------------------------
__global__ __launch_bounds__(512, 2) void scan_kernel(
    const float* __restrict__ xg, const float* __restrict__ Whh,
    float* __restrict__ hs, unsigned long long* hb)
{
    __shared__ float h_s[2][32 * HPAD];   // h[k] at [par][(k>>5)*HPAD + (k&31)]
    const int tid  = threadIdx.x;
    const int u    = tid >> 5;            // unit slot 0..15
    const int s    = tid & 31;            // 32-col segment 0..31
    const int unit = blockIdx.x * 16 + u;

    // weights: 4 gate rows (i,f,g,o) x 32 cols -> 32 float4 in VGPRs
    float4 w4[4][8];
#pragma unroll
    for (int q = 0; q < 4; ++q)
#pragma unroll
        for (int jj = 0; jj < 8; ++jj)
            w4[q][jj] = *(const float4*)(
                Whh + (size_t)(q * HDIM + unit) * KDIM + s * 32 + jj * 4);
#pragma unroll
    for (int q = 0; q < 4; ++q)
#pragma unroll
        for (int jj = 0; jj < 8; ++jj)
            asm volatile("" : "+v"(w4[q][jj].x), "+v"(w4[q][jj].y),
                              "+v"(w4[q][jj].z), "+v"(w4[q][jj].w));

    for (int i = tid; i < 2 * 32 * HPAD; i += SNT) ((float*)h_s)[i] = 0.0f;
    __syncthreads();

    float c = 0.0f;                       // redundant per-lane cell state
    const int sbase = s * HPAD;

    for (int t = 1; t <= NSTEP; ++t) {
        const int par = (t - 1) & 1;

        // xg loads overlap the spin below (lane s<4 fetches gate q=s)
        float xgv = 0.0f;
        if (s < 4) xgv = xg[(size_t)(t - 1) * GDIM + s * HDIM + unit];

        if (t > 1) {
            const int want = t - 1;
            const unsigned long long* p = hb + (size_t)par * HDIM + tid;
            unsigned long long v0 = 0, v1 = 0;
            unsigned pend = 0x3u;
            do {
                if (pend & 1u) v0 = __hip_atomic_load(p,       __ATOMIC_RELAXED, __HIP_MEMORY_SCOPE_AGENT);
                if (pend & 2u) v1 = __hip_atomic_load(p + 512, __ATOMIC_RELAXED, __HIP_MEMORY_SCOPE_AGENT);
                if ((pend & 1u) && (int)(v0 >> 32) == want) pend &= ~1u;
                if ((pend & 2u) && (int)(v1 >> 32) == want) pend &= ~2u;
            } while (pend);
            // seg-major padded store: h[k] -> (k>>5)*HPAD + (k&31)
            h_s[par][u * HPAD + s]        = __uint_as_float((unsigned)v0);
            h_s[par][(u + 16) * HPAD + s] = __uint_as_float((unsigned)v1);
        }
        __syncthreads();   // (B) h_s[par] ready; also fences step t-1 reads
                           // (h_s[par] rewrite at t+2 comes after barrier t+1)

        // GEMV: 32 columns x 4 gate rows, h4 reused across rows
        float a0 = 0.0f, a1 = 0.0f, a2 = 0.0f, a3 = 0.0f;
#pragma unroll
        for (int jj = 0; jj < 8; ++jj) {
            const float4 h4 = *(const float4*)&h_s[par][sbase + jj * 4];
            a0 += w4[0][jj].x * h4.x + w4[0][jj].y * h4.y + w4[0][jj].z * h4.z + w4[0][jj].w * h4.w;
            a1 += w4[1][jj].x * h4.x + w4[1][jj].y * h4.y + w4[1][jj].z * h4.z + w4[1][jj].w * h4.w;
            a2 += w4[2][jj].x * h4.x + w4[2][jj].y * h4.y + w4[2][jj].z * h4.z + w4[2][jj].w * h4.w;
            a3 += w4[3][jj].x * h4.x + w4[3][jj].y * h4.y + w4[3][jj].z * h4.z + w4[3][jj].w * h4.w;
        }
        // fold xg into the right gate accumulator before the reduction
        a0 += (s == 0) ? xgv : 0.0f;
        a1 += (s == 1) ? xgv : 0.0f;
        a2 += (s == 2) ? xgv : 0.0f;
        a3 += (s == 3) ? xgv : 0.0f;
        // 5-stage butterfly over the 32-lane unit-group (masks <32 stay in-group)
#pragma unroll
        for (int m = 1; m < 32; m <<= 1) {
            a0 += __shfl_xor(a0, m, 64);
            a1 += __shfl_xor(a1, m, 64);
            a2 += __shfl_xor(a2, m, 64);
            a3 += __shfl_xor(a3, m, 64);
        }

        const float ig = sigmoidf_(a0);
        const float fg = sigmoidf_(a1);
        const float gg = tanhf_(a2);
        const float og = sigmoidf_(a3);
        c = fg * c + ig * gg;
        const float h = og * tanhf_(c);

        if (s == 0) {
            hs[(size_t)(t - 1) * HDIM + unit] = h;
            const unsigned long long pv =
                ((unsigned long long)(unsigned)t << 32) | __float_as_uint(h);
            __hip_atomic_store(&hb[(size_t)(t & 1) * HDIM + unit], pv,
                               __ATOMIC_RELAXED, __HIP_MEMORY_SCOPE_AGENT);
        }
        // no trailing barrier: parity + barrier(t+1) make h_s WAR-safe;
        // hb overwrite at t+2 is gated by the 2-step handoff slack.
    }
}

extern "C" void kernel_launch(void* const* d_in, const int* in_sizes, int n_in,
                              void* d_out, int out_size, void* d_ws, size_t ws_size,
                              hipStream_t stream)
{
    const int*   x     = (const int*)d_in[0];
    const float* emb   = (const float*)d_in[1];
    const float* W_ih  = (const float*)d_in[2];
    const float* W_hh  = (const float*)d_in[3];
    const float* b_ih  = (const float*)d_in[4];
    const float* b_hh  = (const float*)d_in[5];
    const float* W_out = (const float*)d_in[6];
    const float* b_out = (const float*)d_in[7];
    float* out = (float*)d_out;

    float* xg = (float*)d_ws;                          // 4095*4096 f32
    float* hs = xg + (size_t)NSTEP * GDIM;             // 4095*1024 f32
    unsigned long long* hb =
        (unsigned long long*)(hs + (size_t)NSTEP * HDIM);  // 2*1024 u64 (8B aligned)

    dim3 blk(256);
    dim3 g1(GDIM / 128, 32);                           // 32 x 32
    gemm_emb_kernel<<<g1, blk, 0, stream>>>(x, emb, W_ih, b_ih, b_hh, xg);

    scan_kernel<<<dim3(SNWG), dim3(SNT), 0, stream>>>(xg, W_hh, hs, hb);

    dim3 g2((CDIM + 127) / 128, 32);                   // 10 x 32
    gemm_out_kernel<<<g2, blk, 0, stream>>>(hs, W_out, b_out, out);
}

// Round 4
// 9870.020 us; speedup vs baseline: 1.5875x; 1.4894x over previous
//
#include <hip/hip_runtime.h>
#include <math.h>

#define NSTEP 4095   // T-1 sequence steps
#define EDIM  512
#define HDIM  1024
#define GDIM  4096   // 4*H
#define KDIM  1024   // 2E == H == 1024 for both GEMMs
#define CDIM  1221
#define SNWG  64     // scan workgroups (16 units each) -- proven poll fanout
#define SNT   512    // scan threads per WG (8 waves)
#define HPAD  36     // 32 cols + 4 pad per segment (bank-conflict-free)

// Pin a float4's lanes into VGPRs via an empty asm. Used INSIDE the step
// loop: the value becomes loop-carried through the asm, so the compiler
// cannot rematerialize the weight loads from memory each iteration
// (v3/v5 post-mortem: VGPR_Count 52/84 < weight footprint 64/128 proved
// the W_hh slice was re-read from L2 every step -- the real step cost).
#define PIN4(v) asm volatile("" : "+v"((v).x), "+v"((v).y), "+v"((v).z), "+v"((v).w))

__device__ __forceinline__ float sigmoidf_(float v) {
    return 1.0f / (1.0f + __expf(-v));
}
__device__ __forceinline__ float tanhf_(float v) {
    v = fminf(fmaxf(v, -15.0f), 15.0f);      // avoid inf/inf NaN
    const float e2 = __expf(2.0f * v);
    return (e2 - 1.0f) / (e2 + 1.0f);
}

// ---------------------------------------------------------------------------
// GEMM1: xg[m][n] = sum_k A[m][k]*W_ih[n][k] + b_ih[n] + b_hh[n]
//   A[m][k] = emb[x[m]][k] (k<512) ; emb[x[4095]][k-512] (k>=512)
// ---------------------------------------------------------------------------
__global__ __launch_bounds__(256) void gemm_emb_kernel(
    const int* __restrict__ x, const float* __restrict__ emb,
    const float* __restrict__ W, const float* __restrict__ b_ih,
    const float* __restrict__ b_hh, float* __restrict__ xg)
{
    __shared__ float As[8][128];
    __shared__ float Bs[8][128];
    const int tid = threadIdx.x;
    const int bm = blockIdx.y * 128, bn = blockIdx.x * 128;
    const int tx = tid & 15, ty = tid >> 4;
    const int lrow = tid >> 1;
    const int lk4  = (tid & 1) * 4;
    const int lastTok = x[NSTEP];
    const int am = bm + lrow;
    const int tokRow = (am < NSTEP) ? x[am] : 0;
    const int bnrow = bn + lrow;

    float acc[8][8];
#pragma unroll
    for (int i = 0; i < 8; ++i)
#pragma unroll
        for (int j = 0; j < 8; ++j) acc[i][j] = 0.0f;

    for (int k0 = 0; k0 < KDIM; k0 += 8) {
        const int k = k0 + lk4;
        float4 av = make_float4(0.f, 0.f, 0.f, 0.f);
        if (am < NSTEP) {
            const int tok = (k < EDIM) ? tokRow : lastTok;
            const int kk  = (k < EDIM) ? k : (k - EDIM);
            av = *(const float4*)(emb + (size_t)tok * EDIM + kk);
        }
        const float4 bv = *(const float4*)(W + (size_t)bnrow * KDIM + k);
        __syncthreads();
        As[lk4 + 0][lrow] = av.x; As[lk4 + 1][lrow] = av.y;
        As[lk4 + 2][lrow] = av.z; As[lk4 + 3][lrow] = av.w;
        Bs[lk4 + 0][lrow] = bv.x; Bs[lk4 + 1][lrow] = bv.y;
        Bs[lk4 + 2][lrow] = bv.z; Bs[lk4 + 3][lrow] = bv.w;
        __syncthreads();
#pragma unroll
        for (int kk = 0; kk < 8; ++kk) {
            const float4 a0 = *(const float4*)&As[kk][ty * 4];
            const float4 a1 = *(const float4*)&As[kk][ty * 4 + 64];
            const float4 b0 = *(const float4*)&Bs[kk][tx * 4];
            const float4 b1 = *(const float4*)&Bs[kk][tx * 4 + 64];
            const float a[8] = {a0.x, a0.y, a0.z, a0.w, a1.x, a1.y, a1.z, a1.w};
            const float b[8] = {b0.x, b0.y, b0.z, b0.w, b1.x, b1.y, b1.z, b1.w};
#pragma unroll
            for (int i = 0; i < 8; ++i)
#pragma unroll
                for (int j = 0; j < 8; ++j) acc[i][j] += a[i] * b[j];
        }
    }
#pragma unroll
    for (int i = 0; i < 8; ++i) {
        const int m = bm + ((i < 4) ? (ty * 4 + i) : (64 + ty * 4 + i - 4));
        if (m >= NSTEP) continue;
#pragma unroll
        for (int j = 0; j < 8; ++j) {
            const int n = bn + ((j < 4) ? (tx * 4 + j) : (64 + tx * 4 + j - 4));
            xg[(size_t)m * GDIM + n] = acc[i][j] + b_ih[n] + b_hh[n];
        }
    }
}

// ---------------------------------------------------------------------------
// GEMM2: out[m][n] = sum_k hs[m][k]*W_out[n][k] + b_out[n]   (N=1221)
// ---------------------------------------------------------------------------
__global__ __launch_bounds__(256) void gemm_out_kernel(
    const float* __restrict__ A, const float* __restrict__ W,
    const float* __restrict__ bias, float* __restrict__ C)
{
    __shared__ float As[8][128];
    __shared__ float Bs[8][128];
    const int tid = threadIdx.x;
    const int bm = blockIdx.y * 128, bn = blockIdx.x * 128;
    const int tx = tid & 15, ty = tid >> 4;
    const int lrow = tid >> 1;
    const int lk4  = (tid & 1) * 4;
    const int am = bm + lrow;
    const int bnrow = bn + lrow;

    float acc[8][8];
#pragma unroll
    for (int i = 0; i < 8; ++i)
#pragma unroll
        for (int j = 0; j < 8; ++j) acc[i][j] = 0.0f;

    for (int k0 = 0; k0 < KDIM; k0 += 8) {
        const int k = k0 + lk4;
        float4 av = make_float4(0.f, 0.f, 0.f, 0.f);
        if (am < NSTEP) av = *(const float4*)(A + (size_t)am * KDIM + k);
        float4 bv = make_float4(0.f, 0.f, 0.f, 0.f);
        if (bnrow < CDIM) bv = *(const float4*)(W + (size_t)bnrow * KDIM + k);
        __syncthreads();
        As[lk4 + 0][lrow] = av.x; As[lk4 + 1][lrow] = av.y;
        As[lk4 + 2][lrow] = av.z; As[lk4 + 3][lrow] = av.w;
        Bs[lk4 + 0][lrow] = bv.x; Bs[lk4 + 1][lrow] = bv.y;
        Bs[lk4 + 2][lrow] = bv.z; Bs[lk4 + 3][lrow] = bv.w;
        __syncthreads();
#pragma unroll
        for (int kk = 0; kk < 8; ++kk) {
            const float4 a0 = *(const float4*)&As[kk][ty * 4];
            const float4 a1 = *(const float4*)&As[kk][ty * 4 + 64];
            const float4 b0 = *(const float4*)&Bs[kk][tx * 4];
            const float4 b1 = *(const float4*)&Bs[kk][tx * 4 + 64];
            const float a[8] = {a0.x, a0.y, a0.z, a0.w, a1.x, a1.y, a1.z, a1.w};
            const float b[8] = {b0.x, b0.y, b0.z, b0.w, b1.x, b1.y, b1.z, b1.w};
#pragma unroll
            for (int i = 0; i < 8; ++i)
#pragma unroll
                for (int j = 0; j < 8; ++j) acc[i][j] += a[i] * b[j];
        }
    }
#pragma unroll
    for (int i = 0; i < 8; ++i) {
        const int m = bm + ((i < 4) ? (ty * 4 + i) : (64 + ty * 4 + i - 4));
        if (m >= NSTEP) continue;
#pragma unroll
        for (int j = 0; j < 8; ++j) {
            const int n = bn + ((j < 4) ? (tx * 4 + j) : (64 + tx * 4 + j - 4));
            if (n < CDIM) C[(size_t)m * CDIM + n] = acc[i][j] + bias[n];
        }
    }
}

// ---------------------------------------------------------------------------
// Persistent LSTM scan, v6 = v5 + TRUE weight residency (resubmission; the
// Round-3 bench failed with a container-level infra error, no kernel data).
// 64 WGs x 512 threads (8 waves); WG g owns units g*16..g*16+15. Thread
// (u = tid>>5, s = tid&31) holds ALL FOUR gate rows of unit u restricted to
// columns s*32..s*32+31 (4x8 float4 = 128 weight VGPRs).
// The PIN4 block inside the step loop makes every weight value loop-carried
// through an empty asm -> the compiler can no longer rematerialize the W_hh
// loads from L2 each step (v5's hidden cost: 256KB of L2 reads per CU per
// step in 32-deep latency chains with only 2 waves/SIMD to hide them).
// Handoff/layout/tail identical to v5 (verified correct twice).
// ---------------------------------------------------------------------------
__global__ __launch_bounds__(512, 2) void scan_kernel(
    const float* __restrict__ xg, const float* __restrict__ Whh,
    float* __restrict__ hs, unsigned long long* hb)
{
    __shared__ float h_s[2][32 * HPAD];   // h[k] at [par][(k>>5)*HPAD + (k&31)]
    const int tid  = threadIdx.x;
    const int u    = tid >> 5;            // unit slot 0..15
    const int s    = tid & 31;            // 32-col segment 0..31
    const int unit = blockIdx.x * 16 + u;

    // weights: 4 gate rows (i,f,g,o) x 32 cols -> 32 float4 in VGPRs
    float4 w4[4][8];
#pragma unroll
    for (int q = 0; q < 4; ++q)
#pragma unroll
        for (int jj = 0; jj < 8; ++jj)
            w4[q][jj] = *(const float4*)(
                Whh + (size_t)(q * HDIM + unit) * KDIM + s * 32 + jj * 4);

    for (int i = tid; i < 2 * 32 * HPAD; i += SNT) ((float*)h_s)[i] = 0.0f;
    __syncthreads();

    float c = 0.0f;                       // redundant per-lane cell state
    const int sbase = s * HPAD;

    for (int t = 1; t <= NSTEP; ++t) {
        // Residency pin: weights pass through an empty asm EVERY iteration,
        // making them loop-carried -> no remat-from-memory possible.
#pragma unroll
        for (int q = 0; q < 4; ++q) {
            PIN4(w4[q][0]); PIN4(w4[q][1]); PIN4(w4[q][2]); PIN4(w4[q][3]);
            PIN4(w4[q][4]); PIN4(w4[q][5]); PIN4(w4[q][6]); PIN4(w4[q][7]);
        }

        const int par = (t - 1) & 1;

        // xg loads overlap the spin below (lane s<4 fetches gate q=s)
        float xgv = 0.0f;
        if (s < 4) xgv = xg[(size_t)(t - 1) * GDIM + s * HDIM + unit];

        if (t > 1) {
            const int want = t - 1;
            const unsigned long long* p = hb + (size_t)par * HDIM + tid;
            unsigned long long v0 = 0, v1 = 0;
            unsigned pend = 0x3u;
            do {
                if (pend & 1u) v0 = __hip_atomic_load(p,       __ATOMIC_RELAXED, __HIP_MEMORY_SCOPE_AGENT);
                if (pend & 2u) v1 = __hip_atomic_load(p + 512, __ATOMIC_RELAXED, __HIP_MEMORY_SCOPE_AGENT);
                if ((pend & 1u) && (int)(v0 >> 32) == want) pend &= ~1u;
                if ((pend & 2u) && (int)(v1 >> 32) == want) pend &= ~2u;
            } while (pend);
            // seg-major padded store: h[k] -> (k>>5)*HPAD + (k&31)
            h_s[par][u * HPAD + s]        = __uint_as_float((unsigned)v0);
            h_s[par][(u + 16) * HPAD + s] = __uint_as_float((unsigned)v1);
        }
        __syncthreads();   // (B) h_s[par] ready; also fences step t-1 reads
                           // (h_s[par] rewrite at t+2 comes after barrier t+1)

        // GEMV: 32 columns x 4 gate rows, h4 reused across rows, W in VGPRs
        float a0 = 0.0f, a1 = 0.0f, a2 = 0.0f, a3 = 0.0f;
#pragma unroll
        for (int jj = 0; jj < 8; ++jj) {
            const float4 h4 = *(const float4*)&h_s[par][sbase + jj * 4];
            a0 += w4[0][jj].x * h4.x + w4[0][jj].y * h4.y + w4[0][jj].z * h4.z + w4[0][jj].w * h4.w;
            a1 += w4[1][jj].x * h4.x + w4[1][jj].y * h4.y + w4[1][jj].z * h4.z + w4[1][jj].w * h4.w;
            a2 += w4[2][jj].x * h4.x + w4[2][jj].y * h4.y + w4[2][jj].z * h4.z + w4[2][jj].w * h4.w;
            a3 += w4[3][jj].x * h4.x + w4[3][jj].y * h4.y + w4[3][jj].z * h4.z + w4[3][jj].w * h4.w;
        }
        // fold xg into the right gate accumulator before the reduction
        a0 += (s == 0) ? xgv : 0.0f;
        a1 += (s == 1) ? xgv : 0.0f;
        a2 += (s == 2) ? xgv : 0.0f;
        a3 += (s == 3) ? xgv : 0.0f;
        // 5-stage butterfly over the 32-lane unit-group (masks <32 stay in-group)
#pragma unroll
        for (int m = 1; m < 32; m <<= 1) {
            a0 += __shfl_xor(a0, m, 64);
            a1 += __shfl_xor(a1, m, 64);
            a2 += __shfl_xor(a2, m, 64);
            a3 += __shfl_xor(a3, m, 64);
        }

        const float ig = sigmoidf_(a0);
        const float fg = sigmoidf_(a1);
        const float gg = tanhf_(a2);
        const float og = sigmoidf_(a3);
        c = fg * c + ig * gg;
        const float h = og * tanhf_(c);

        if (s == 0) {
            hs[(size_t)(t - 1) * HDIM + unit] = h;
            const unsigned long long pv =
                ((unsigned long long)(unsigned)t << 32) | __float_as_uint(h);
            __hip_atomic_store(&hb[(size_t)(t & 1) * HDIM + unit], pv,
                               __ATOMIC_RELAXED, __HIP_MEMORY_SCOPE_AGENT);
        }
        // no trailing barrier: parity + barrier(t+1) make h_s WAR-safe;
        // hb overwrite at t+2 is gated by the 2-step handoff slack.
    }
}

extern "C" void kernel_launch(void* const* d_in, const int* in_sizes, int n_in,
                              void* d_out, int out_size, void* d_ws, size_t ws_size,
                              hipStream_t stream)
{
    const int*   x     = (const int*)d_in[0];
    const float* emb   = (const float*)d_in[1];
    const float* W_ih  = (const float*)d_in[2];
    const float* W_hh  = (const float*)d_in[3];
    const float* b_ih  = (const float*)d_in[4];
    const float* b_hh  = (const float*)d_in[5];
    const float* W_out = (const float*)d_in[6];
    const float* b_out = (const float*)d_in[7];
    float* out = (float*)d_out;

    float* xg = (float*)d_ws;                          // 4095*4096 f32
    float* hs = xg + (size_t)NSTEP * GDIM;             // 4095*1024 f32
    unsigned long long* hb =
        (unsigned long long*)(hs + (size_t)NSTEP * HDIM);  // 2*1024 u64 (8B aligned)

    dim3 blk(256);
    dim3 g1(GDIM / 128, 32);                           // 32 x 32
    gemm_emb_kernel<<<g1, blk, 0, stream>>>(x, emb, W_ih, b_ih, b_hh, xg);

    scan_kernel<<<dim3(SNWG), dim3(SNT), 0, stream>>>(xg, W_hh, hs, hb);

    dim3 g2((CDIM + 127) / 128, 32);                   // 10 x 32
    gemm_out_kernel<<<g2, blk, 0, stream>>>(hs, W_out, b_out, out);
}